// Round 3
// baseline (5045.898 us; speedup 1.0000x reference)
//
#include <hip/hip_runtime.h>

typedef __attribute__((ext_vector_type(8))) short short8v;
typedef __attribute__((ext_vector_type(4))) float f32x4;
typedef __attribute__((ext_vector_type(4))) float float4v;
typedef unsigned int u32;
typedef unsigned long long u64;

#define NT 512
#define SLOT 8192                       // shorts per ring slot per team (8 rows x 1024)
#define RING_TEAM ((size_t)513 * SLOT)  // shorts per team ring
#define RING_BYTES ((size_t)8 * RING_TEAM * 2)

__device__ __forceinline__ short f2bf(float f) {
  union { float f; unsigned u; } c; c.f = f;
  unsigned r = (c.u + 0x7fffu + ((c.u >> 16) & 1u)) >> 16;
  return (short)r;
}

__device__ __forceinline__ short8v cvt8(float4v a, float4v b) {
  short8v s;
  s[0]=f2bf(a[0]); s[1]=f2bf(a[1]); s[2]=f2bf(a[2]); s[3]=f2bf(a[3]);
  s[4]=f2bf(b[0]); s[5]=f2bf(b[1]); s[6]=f2bf(b[2]); s[7]=f2bf(b[3]);
  return s;
}

union V16 { short8v v; u32 w[4]; u64 q[2]; };

// L1-bypassing, L2-hitting 16B load (fast poll path; proven sc0 semantics in r0)
__device__ __forceinline__ short8v ld16_sc0(const short* p) {
  short8v r;
  asm volatile("global_load_dwordx4 %0, %1, off sc0" : "=v"(r) : "v"(p));
  return r;
}

// MALL (agent-scope) 16B load — correctness fallback, proven in r1
__device__ __forceinline__ short8v ald16(const short* p) {
  V16 u;
  u.q[0] = __hip_atomic_load((const u64*)p,     __ATOMIC_RELAXED, __HIP_MEMORY_SCOPE_AGENT);
  u.q[1] = __hip_atomic_load((const u64*)p + 1, __ATOMIC_RELAXED, __HIP_MEMORY_SCOPE_AGENT);
  return u.v;
}

// per-16-bit sentinel check (2B stores can't tear a 16-bit unit)
__device__ __forceinline__ u32 sentchk(short8v f) {
  V16 u; u.v = f;
  u32 b = 0;
#pragma unroll
  for (int q = 0; q < 4; ++q) {
    b |= ((u.w[q] & 0xFFFFu) == 0xFFFFu);
    b |= ((u.w[q] >> 16) == 0xFFFFu);
  }
  return b;
}

// Sentinel poll with stale-L2 discrimination:
//  fast path: sc0 (shared-L2) loads. If stuck 32 iters, probe MALL: data there
//  but not in L2 => cross-XCD placement => permanently escalate to MALL loads;
//  MALL also sentinel => producer genuinely behind => keep fast polling.
template<int N>
__device__ __forceinline__ void poll_tile(const short* hr, bool vld, bool& slow, short8v* a8) {
  int spin = 0;
  for (;;) {
    u32 bad = 0;
    if (!slow) {
      if (vld) {
#pragma unroll
        for (int i = 0; i < N; ++i) a8[i] = ld16_sc0(hr + i * 32);
      }
      asm volatile("s_waitcnt vmcnt(0)" ::: "memory");
      __builtin_amdgcn_sched_barrier(0);
      if (vld) {
#pragma unroll
        for (int i = 0; i < N; ++i) bad |= sentchk(a8[i]);
      }
      if (__ballot(bad != 0) == 0ull) return;
      if ((++spin & 31) == 0) {
        u32 badp = 0;
        if (vld) {
#pragma unroll
          for (int i = 0; i < N; ++i) { a8[i] = ald16(hr + i * 32); badp |= sentchk(a8[i]); }
        }
        if (__ballot(badp != 0) == 0ull) { slow = true; return; }
      }
    } else {
      if (vld) {
#pragma unroll
        for (int i = 0; i < N; ++i) { a8[i] = ald16(hr + i * 32); bad |= sentchk(a8[i]); }
      }
      if (__ballot(bad != 0) == 0ull) return;
    }
    __builtin_amdgcn_s_sleep(1);
  }
}

// ---------------------------------------------------------------------------
// Batch-parallel GRU. 256 wgs x 256 thr, 96KB LDS => 1 wg/CU (hard co-residency).
// Team p = blockIdx&7 (XCD under round-robin dispatch — heuristic only) owns
// batch rows 8p..8p+8; wg s = blockIdx>>3 owns h-cols 32s..32s+32.
// Waves 0,1: h-half MFMA (K=512 each), U-frags in registers, NO global stores
//   => their poll vmcnt covers only poll loads. Waves 2,3: x-projection on the
//   fly (K=512 each, W-frags in registers, next-t x prefetched under MFMAs)
//   + entire epilogue (reduce, gates, dual-store publish).
// h handoff: sentinel-in-data (ring pre-memset 0xFF = bf16 NaN, unreachable),
// dual-store (plain => shared per-XCD L2; agent-atomic => MALL), consumers
// poll data with sc0 loads + MALL-probe escalation. No flags, no drains.
// ---------------------------------------------------------------------------
__global__ __launch_bounds__(256, 1) void gru_kernel(
    const float* __restrict__ h0, const float* __restrict__ Wh, const float* __restrict__ Wz,
    const float* __restrict__ Uh, const float* __restrict__ Uz, const float* __restrict__ bz,
    const float* __restrict__ Wout, const float* __restrict__ x,
    short* __restrict__ ring, float* __restrict__ out)
{
  extern __shared__ char smem[];
  float* red = (float*)smem;   // [2 par][4 wv][16 slot][64 lane] = 32 KB

  // one-time: invalidate stale cross-launch lines (clean-stale ring lines die here)
  __builtin_amdgcn_fence(__ATOMIC_ACQUIRE, "agent");

  const int tid  = threadIdx.x;
  const int lane = tid & 63;
  const int wv   = tid >> 6;
  const int colL = lane & 15;
  const int quad = lane >> 4;
  const int kq   = quad * 8;
  const int p    = blockIdx.x & 7;
  const int s    = blockIdx.x >> 3;
  const int RB   = p * 8;
  const int JB   = s * 32;
  short* ringp = ring + (size_t)p * RING_TEAM;
  const bool isH = wv < 2;
  const bool vld = colL < 8;

  // ---- weights into registers: 16 kb x {z,h} x {ct0,ct1} = 256 VGPR ----
  short8v bw[16][4];
  {
    const float* M0 = isH ? Uz : Wz;
    const float* M1 = isH ? Uh : Wh;
    const int kb = (isH ? wv : (wv - 2)) * 512;
#pragma unroll
    for (int i = 0; i < 16; ++i)
#pragma unroll
      for (int j = 0; j < 4; ++j) {
        const float* M = (j >> 1) ? M1 : M0;
        const float* mr = M + (size_t)(JB + (j & 1) * 16 + colL) * 1024 + kb + i * 32 + kq;
        bw[i][j] = cvt8(*(const float4v*)mr, *(const float4v*)(mr + 4));
      }
  }

  // ---- epilogue state (x-waves): thread owns rows er, er+4 at col ec ----
  short8v xs8[16];
  float hl0 = 0.f, hl1 = 0.f, bzv = 0.f;
  int er = 0, ec = 0, ect = 0, elsrc0 = 0, elsrc1 = 0;
  if (!isH) {
    const int tid2 = tid - 128;
    er = tid2 >> 5; ec = tid2 & 31;
    ect = ec >> 4; elsrc0 = ec & 15; elsrc1 = 16 + (ec & 15);
    hl0 = h0[(size_t)(RB + er) * 1024 + JB + ec];
    hl1 = h0[(size_t)(RB + er + 4) * 1024 + JB + ec];
    bzv = bz[JB + ec];
    const float* xr0 = x + ((size_t)(RB + colL) * NT) * 1024 + (wv - 2) * 512 + kq;
#pragma unroll
    for (int i = 0; i < 16; ++i) {
      short8v zz = {};
      xs8[i] = vld ? cvt8(*(const float4v*)(xr0 + i * 32), *(const float4v*)(xr0 + i * 32 + 4)) : zz;
    }
  }

  bool slow = false;

  // =========================== RECURRENCE ==================================
  for (int t = 0; t < NT; ++t) {
    const int par = t & 1;
    f32x4 ac0 = {0.f,0.f,0.f,0.f}, ac1 = ac0, ac2 = ac0, ac3 = ac0;

    if (isH) {
      short8v a8[16] = {};
      if (t == 0) {
        const float* hr0 = h0 + (size_t)(RB + colL) * 1024 + wv * 512 + kq;
        if (vld) {
#pragma unroll
          for (int i = 0; i < 16; ++i)
            a8[i] = cvt8(*(const float4v*)(hr0 + i * 32), *(const float4v*)(hr0 + i * 32 + 4));
        }
      } else {
        const short* hr = ringp + (size_t)t * SLOT + colL * 1024 + wv * 512 + kq;
        poll_tile<16>(hr, vld, slow, a8);
      }
#pragma unroll
      for (int i = 0; i < 16; ++i) {
        ac0 = __builtin_amdgcn_mfma_f32_16x16x32_bf16(a8[i], bw[i][0], ac0, 0, 0, 0);
        ac1 = __builtin_amdgcn_mfma_f32_16x16x32_bf16(a8[i], bw[i][1], ac1, 0, 0, 0);
        ac2 = __builtin_amdgcn_mfma_f32_16x16x32_bf16(a8[i], bw[i][2], ac2, 0, 0, 0);
        ac3 = __builtin_amdgcn_mfma_f32_16x16x32_bf16(a8[i], bw[i][3], ac3, 0, 0, 0);
      }
    } else {
      // x-wave: MFMA on xs8(t) while prefetching x(t+1) in two halves
      const bool pf = vld && (t + 1 < NT);
      const float* xr = x + ((size_t)(RB + colL) * NT + (t + 1 < NT ? t + 1 : t)) * 1024
                          + (wv - 2) * 512 + kq;
      float4v g0[8], g1[8];
      if (pf) {
#pragma unroll
        for (int i = 0; i < 8; ++i) {
          g0[i] = *(const float4v*)(xr + i * 32);
          g1[i] = *(const float4v*)(xr + i * 32 + 4);
        }
      }
#pragma unroll
      for (int i = 0; i < 8; ++i) {
        ac0 = __builtin_amdgcn_mfma_f32_16x16x32_bf16(xs8[i], bw[i][0], ac0, 0, 0, 0);
        ac1 = __builtin_amdgcn_mfma_f32_16x16x32_bf16(xs8[i], bw[i][1], ac1, 0, 0, 0);
        ac2 = __builtin_amdgcn_mfma_f32_16x16x32_bf16(xs8[i], bw[i][2], ac2, 0, 0, 0);
        ac3 = __builtin_amdgcn_mfma_f32_16x16x32_bf16(xs8[i], bw[i][3], ac3, 0, 0, 0);
      }
      if (pf) {
#pragma unroll
        for (int i = 0; i < 8; ++i) xs8[i] = cvt8(g0[i], g1[i]);
#pragma unroll
        for (int i = 0; i < 8; ++i) {
          g0[i] = *(const float4v*)(xr + 256 + i * 32);
          g1[i] = *(const float4v*)(xr + 256 + i * 32 + 4);
        }
      }
#pragma unroll
      for (int i = 8; i < 16; ++i) {
        ac0 = __builtin_amdgcn_mfma_f32_16x16x32_bf16(xs8[i], bw[i][0], ac0, 0, 0, 0);
        ac1 = __builtin_amdgcn_mfma_f32_16x16x32_bf16(xs8[i], bw[i][1], ac1, 0, 0, 0);
        ac2 = __builtin_amdgcn_mfma_f32_16x16x32_bf16(xs8[i], bw[i][2], ac2, 0, 0, 0);
        ac3 = __builtin_amdgcn_mfma_f32_16x16x32_bf16(xs8[i], bw[i][3], ac3, 0, 0, 0);
      }
      if (pf) {
#pragma unroll
        for (int i = 0; i < 8; ++i) xs8[8 + i] = cvt8(g0[i], g1[i]);
      }
    }

    // partials: [wv][job j][reg] x lane — conflict-free
    {
      float* rb = red + par * 4096 + (wv * 16) * 64 + lane;
#pragma unroll
      for (int reg = 0; reg < 4; ++reg) {
        rb[(0 * 4 + reg) * 64] = ac0[reg];
        rb[(1 * 4 + reg) * 64] = ac1[reg];
        rb[(2 * 4 + reg) * 64] = ac2[reg];
        rb[(3 * 4 + reg) * 64] = ac3[reg];
      }
    }
    __syncthreads();

    // epilogue: x-waves only (h-waves go straight to next poll, store-free)
    if (!isH) {
      float az0 = 0.f, ah0 = 0.f, az1 = 0.f, ah1 = 0.f;
#pragma unroll
      for (int w = 0; w < 4; ++w) {
        const float* rb = red + par * 4096 + (w * 16) * 64;
        az0 += rb[(ect * 4 + er) * 64 + elsrc0];
        ah0 += rb[((2 + ect) * 4 + er) * 64 + elsrc0];
        az1 += rb[(ect * 4 + er) * 64 + elsrc1];
        ah1 += rb[((2 + ect) * 4 + er) * 64 + elsrc1];
      }
      float z0 = 1.f / (1.f + __expf(-(az0 + bzv)));
      float h0v = 2.f / (1.f + __expf(-2.f * ah0)) - 1.f;   // tanh, overflow-safe
      hl0 += z0 * (h0v - hl0);
      float z1 = 1.f / (1.f + __expf(-(az1 + bzv)));
      float h1v = 2.f / (1.f + __expf(-2.f * ah1)) - 1.f;
      hl1 += z1 * (h1v - hl1);
      short v0 = f2bf(hl0), v1 = f2bf(hl1);
      short* d0 = ringp + (size_t)(t + 1) * SLOT + er * 1024 + JB + ec;
      short* d1 = d0 + 4 * 1024;
      *(volatile short*)d0 = v0;                                          // XCD L2 (fast path)
      __hip_atomic_store(d0, v0, __ATOMIC_RELAXED, __HIP_MEMORY_SCOPE_AGENT); // MALL (correctness)
      *(volatile short*)d1 = v1;
      __hip_atomic_store(d1, v1, __ATOMIC_RELAXED, __HIP_MEMORY_SCOPE_AGENT);
    }
  }

  // ======================= TAIL: out = hT @ Wout^T =========================
  {
    short8v a8t[8] = {};
    const short* hrt = ringp + (size_t)NT * SLOT + colL * 1024 + wv * 256 + kq;
    poll_tile<8>(hrt, vld, slow, a8t);
    f32x4 oc0 = {0.f,0.f,0.f,0.f}, oc1 = oc0;
#pragma unroll
    for (int i = 0; i < 8; ++i) {
      const float* w0 = Wout + (size_t)(JB + colL) * 1024 + wv * 256 + i * 32 + kq;
      const float* w1 = Wout + (size_t)(JB + 16 + colL) * 1024 + wv * 256 + i * 32 + kq;
      oc0 = __builtin_amdgcn_mfma_f32_16x16x32_bf16(
              a8t[i], cvt8(*(const float4v*)w0, *(const float4v*)(w0 + 4)), oc0, 0, 0, 0);
      oc1 = __builtin_amdgcn_mfma_f32_16x16x32_bf16(
              a8t[i], cvt8(*(const float4v*)w1, *(const float4v*)(w1 + 4)), oc1, 0, 0, 0);
    }
    {
      float* rb = red + (wv * 8) * 64 + lane;
#pragma unroll
      for (int reg = 0; reg < 4; ++reg) {
        rb[reg * 64]       = oc0[reg];
        rb[(4 + reg) * 64] = oc1[reg];
      }
    }
    __syncthreads();
    if (!isH) {
      float o0 = 0.f, o1 = 0.f;
#pragma unroll
      for (int w = 0; w < 4; ++w) {
        o0 += red[(w * 8 + ect * 4 + er) * 64 + elsrc0];
        o1 += red[(w * 8 + ect * 4 + er) * 64 + elsrc1];
      }
      out[(size_t)(RB + er) * 1024 + JB + ec]     = o0;
      out[(size_t)(RB + er + 4) * 1024 + JB + ec] = o1;
    }
  }
}

extern "C" void kernel_launch(void* const* d_in, const int* in_sizes, int n_in,
                              void* d_out, int out_size, void* d_ws, size_t ws_size,
                              hipStream_t stream) {
  const float* x    = (const float*)d_in[0];
  const float* h0   = (const float*)d_in[1];
  const float* Wh   = (const float*)d_in[2];
  const float* Wz   = (const float*)d_in[3];
  const float* Uh   = (const float*)d_in[5];
  const float* Uz   = (const float*)d_in[6];
  const float* bz   = (const float*)d_in[8];
  const float* Wout = (const float*)d_in[10];

  // workspace: h-ring only, 8 teams x 513 slots x 16KB = 67.2 MB (proven size)
  short* ring = (short*)d_ws;
  hipMemsetAsync(ring, 0xFF, RING_BYTES, stream);   // sentinel fill

  hipFuncSetAttribute((const void*)gru_kernel,
                      hipFuncAttributeMaxDynamicSharedMemorySize, 98304);
  gru_kernel<<<256, 256, 98304, stream>>>(h0, Wh, Wz, Uh, Uz, bz, Wout, x,
                                          ring, (float*)d_out);
}

// Round 4
// 4323.297 us; speedup vs baseline: 1.1671x; 1.1671x over previous
//
#include <hip/hip_runtime.h>

typedef __attribute__((ext_vector_type(8))) short short8v;
typedef __attribute__((ext_vector_type(4))) float f32x4;
typedef __attribute__((ext_vector_type(4))) float float4v;
typedef unsigned int u32;
typedef unsigned long long u64;

#define NT 512
#define SLOT 8192                       // shorts per ring slot (8 rows x 1024)
#define RING_TEAM ((size_t)(NT + 1) * SLOT)
#define RING_BYTES ((size_t)8 * RING_TEAM * 2)

__device__ __forceinline__ short f2bf(float f) {
  union { float f; unsigned u; } c; c.f = f;
  unsigned r = (c.u + 0x7fffu + ((c.u >> 16) & 1u)) >> 16;
  return (short)r;
}

__device__ __forceinline__ short8v cvt8(float4v a, float4v b) {
  short8v s;
  s[0]=f2bf(a[0]); s[1]=f2bf(a[1]); s[2]=f2bf(a[2]); s[3]=f2bf(a[3]);
  s[4]=f2bf(b[0]); s[5]=f2bf(b[1]); s[6]=f2bf(b[2]); s[7]=f2bf(b[3]);
  return s;
}

union V16 { short8v v; u32 w[4]; u64 q[2]; };

// MALL-direct 16B load/store: sc0 (L1 bypass) + sc1 (L2 bypass) = agent scope,
// same cache behavior as __hip_atomic_load/store(AGENT) (proven r1/r3) but
// issued as plain VMEM ops so a whole sweep pipelines under ONE vmcnt(0).
__device__ __forceinline__ short8v ld16_mall(const short* p) {
  short8v r;
  asm volatile("global_load_dwordx4 %0, %1, off sc0 sc1" : "=v"(r) : "v"(p));
  return r;
}
__device__ __forceinline__ void st16_mall(short* p, short8v v) {
  asm volatile("global_store_dwordx4 %0, %1, off sc0 sc1" :: "v"(p), "v"(v) : "memory");
}

// per-16-bit sentinel check (2B granules can't tear)
__device__ __forceinline__ u32 sentchk(short8v f) {
  V16 u; u.v = f;
  u32 b = 0;
#pragma unroll
  for (int q = 0; q < 4; ++q) {
    b |= ((u.w[q] & 0xFFFFu) == 0xFFFFu);
    b |= ((u.w[q] >> 16) == 0xFFFFu);
  }
  return b;
}

// Sentinel poll, MALL-direct, pipelined, with per-producer-stripe done-mask:
// each 16B tile i is owned by exactly one producer wg; once a stripe passes it
// is never re-fetched, so steady-state poll traffic is only the late stripes.
template<int N>
__device__ __forceinline__ void poll_mall(const short* hr, short8v* a8) {
  u32 done = 0;
  const u32 all = (1u << N) - 1u;
  for (;;) {
#pragma unroll
    for (int i = 0; i < N; ++i)
      if (!(done & (1u << i))) a8[i] = ld16_mall(hr + i * 32);
    asm volatile("s_waitcnt vmcnt(0)" ::: "memory");
    __builtin_amdgcn_sched_barrier(0);
    u32 nd = done;
#pragma unroll
    for (int i = 0; i < N; ++i)
      if (!(done & (1u << i)))
        if (__ballot(sentchk(a8[i]) != 0u) == 0ull) nd |= (1u << i);
    done = nd;
    if (done == all) return;
    __builtin_amdgcn_s_sleep(1);
  }
}

// ---------------------------------------------------------------------------
// Batch-parallel GRU, 256 wgs x 512 thr (8 waves), 88KB LDS => 1 wg/CU.
// Team p = blockIdx&7 owns batch rows 8p..+8; wg s = blockIdx>>3 owns h-cols
// 32s..+32. Wave role = (side, gate, K-half): wv0-3 h-side, wv4-7 x-side.
// Per wave: weight B-frags bw[16][2] = 128 VGPR (fits! r3 spilled at 256+).
// x staged via double-buffered LDS (bf16, subtiled [kh][kc][row][8k] => 
// conflict-free ds_read_b128), pipeline: gloads(t+3) -> regs(32) -> ds_write
// at t+1 into buf[(t+3)&1]... (issue at t, write at t+1, read at t+3-1? see
// loop: write x(t+2) at step t post-barrier, read at t+2 pre-barrier: the
// intervening barrier(t+1) orders cross-wave).
// h handoff: sentinel ring (memset 0xFF = bf16 NaN, unreachable; kernel-end
// release of the memset kernel flushes it to MALL). Producers: fire-and-
// forget 16B sc0sc1 stores, NO drain, NO flag. Consumers: poll_mall above.
// Placement-independent: every ring access is MALL-scope. No deadlock, no
// escalation path, no serialized atomics.
// ---------------------------------------------------------------------------
__global__ __launch_bounds__(512, 2) void gru_kernel(
    const float* __restrict__ h0, const float* __restrict__ Wh, const float* __restrict__ Wz,
    const float* __restrict__ Uh, const float* __restrict__ Uz, const float* __restrict__ bz,
    const float* __restrict__ Wout, const float* __restrict__ x,
    short* __restrict__ ring, float* __restrict__ out)
{
  extern __shared__ char smem[];
  float* red  = (float*)smem;              // [2 par][16 slot][4 reg][64 lane] = 32 KB
  short* xbuf = (short*)(smem + 32768);    // [2 buf][2 kh][64 kc][8 row][8 k] bf16 = 32 KB
  short* rp   = (short*)(smem + 65536);    // 4 x-waves x 128 B repack

  // one-time: kill cross-launch stale lines in L1/L2 (weights/x/h0 reads)
  __builtin_amdgcn_fence(__ATOMIC_ACQUIRE, "agent");

  const int tid  = threadIdx.x;
  const int lane = tid & 63;
  const int wv   = tid >> 6;
  const int colL = lane & 15;
  const int rowA = lane & 7;          // duplicate rows for lanes 8-15 (C rows 8-15 unused)
  const int quad = lane >> 4;
  const int kq   = quad * 8;
  const int p    = blockIdx.x & 7;
  const int s    = blockIdx.x >> 3;
  const int RB   = p * 8;
  const int JB   = s * 32;
  short* ringp = ring + (size_t)p * RING_TEAM;
  const bool isH = wv < 4;
  const int g    = (wv & 3) >> 1;     // gate: 0=z, 1=htilde
  const int kh   = wv & 1;            // K-half
  const int xw   = wv - 4;

  // ---- weights into registers: 16 kb x 2 col-tiles = 128 VGPR ----
  short8v bw[16][2];
  {
    const float* M = isH ? (g ? Uh : Uz) : (g ? Wh : Wz);
#pragma unroll
    for (int i = 0; i < 16; ++i)
#pragma unroll
      for (int j = 0; j < 2; ++j) {
        const float* mr = M + (size_t)(JB + j * 16 + colL) * 1024 + kh * 512 + i * 32 + kq;
        bw[i][j] = cvt8(*(const float4v*)mr, *(const float4v*)(mr + 4));
      }
  }

  // ---- epilogue state (x-waves): 1 value/lane, row er col ec ----
  float hl = 0.f, bzv = 0.f;
  int er = 0, ec = 0;
  if (!isH) {
    er  = xw * 2 + (lane >> 5);
    ec  = lane & 31;
    hl  = h0[(size_t)(RB + er) * 1024 + JB + ec];
    bzv = bz[JB + ec];
  }
  const int rg   = er & 3;
  const int ctE  = ec >> 4;
  const int lsrc = (er >> 2) * 16 + (ec & 15);

  // ---- x staging prologue: buf0=x(0), buf1=x(1); issue x(2) into regs ----
  float4v gA[4], gB[4];
  if (!isH) {
#pragma unroll
    for (int b = 0; b < 2; ++b) {
      float4v ta[4], tb[4];
#pragma unroll
      for (int j = 0; j < 4; ++j) {
        const int so = xw * 2048 + j * 512 + lane * 8;   // shorts into one 16KB buf
        const float* src = x + ((size_t)(RB + ((so >> 3) & 7)) * NT + b) * 1024
                         + (so >> 12) * 512 + ((so >> 6) & 63) * 8;
        ta[j] = *(const float4v*)src; tb[j] = *(const float4v*)(src + 4);
      }
#pragma unroll
      for (int j = 0; j < 4; ++j)
        *(short8v*)(xbuf + b * 8192 + xw * 2048 + j * 512 + lane * 8) = cvt8(ta[j], tb[j]);
    }
#pragma unroll
    for (int j = 0; j < 4; ++j) {
      const int so = xw * 2048 + j * 512 + lane * 8;
      const float* src = x + ((size_t)(RB + ((so >> 3) & 7)) * NT + 2) * 1024
                       + (so >> 12) * 512 + ((so >> 6) & 63) * 8;
      gA[j] = *(const float4v*)src; gB[j] = *(const float4v*)(src + 4);
    }
  }
  __syncthreads();

  // =========================== RECURRENCE ==================================
  for (int t = 0; t < NT; ++t) {
    const int par = t & 1;
    f32x4 ac0 = {0.f,0.f,0.f,0.f}, ac1 = ac0;

    if (isH) {
      short8v a8[16];
      if (t == 0) {
        const float* hr0 = h0 + (size_t)(RB + rowA) * 1024 + kh * 512 + kq;
#pragma unroll
        for (int i = 0; i < 16; ++i)
          a8[i] = cvt8(*(const float4v*)(hr0 + i * 32), *(const float4v*)(hr0 + i * 32 + 4));
      } else {
        poll_mall<16>(ringp + (size_t)t * SLOT + rowA * 1024 + kh * 512 + kq, a8);
      }
#pragma unroll
      for (int i = 0; i < 16; ++i) {
        ac0 = __builtin_amdgcn_mfma_f32_16x16x32_bf16(a8[i], bw[i][0], ac0, 0, 0, 0);
        ac1 = __builtin_amdgcn_mfma_f32_16x16x32_bf16(a8[i], bw[i][1], ac1, 0, 0, 0);
      }
    } else {
      const short* xb = xbuf + par * 8192 + kh * 4096 + quad * 64 + rowA * 8;
#pragma unroll
      for (int i = 0; i < 16; ++i) {
        short8v a = *(const short8v*)(xb + i * 256);
        ac0 = __builtin_amdgcn_mfma_f32_16x16x32_bf16(a, bw[i][0], ac0, 0, 0, 0);
        ac1 = __builtin_amdgcn_mfma_f32_16x16x32_bf16(a, bw[i][1], ac1, 0, 0, 0);
      }
    }

    // partials: slot = wv*2 + ct, lane-stride-1 (conflict-free)
    {
      float* rb = red + par * 4096 + (wv * 8) * 64 + lane;
#pragma unroll
      for (int reg = 0; reg < 4; ++reg) {
        rb[reg * 64]       = ac0[reg];
        rb[(4 + reg) * 64] = ac1[reg];
      }
    }
    __syncthreads();

    // epilogue: x-waves only (h-waves go straight to next poll)
    if (!isH) {
      float az = 0.f, ah = 0.f;
      const float* rb = red + par * 4096;
#pragma unroll
      for (int q2 = 0; q2 < 4; ++q2) {
        const int zs[4] = {0, 2, 8, 10};     // z-gate slots (waves 0,1,4,5)
        az += rb[((zs[q2] + ctE) * 4 + rg) * 64 + lsrc];
        ah += rb[((zs[q2] + 4 + ctE) * 4 + rg) * 64 + lsrc];
      }
      float z  = 1.f / (1.f + __expf(-(az + bzv)));
      float ht = 2.f / (1.f + __expf(-2.f * ah)) - 1.f;   // tanh, overflow-safe
      hl += z * (ht - hl);
      rp[xw * 64 + (lane >> 5) * 32 + (lane & 31)] = f2bf(hl);
      __asm__ volatile("s_waitcnt lgkmcnt(0)" ::: "memory");   // wave-internal LDS RAW
      __builtin_amdgcn_sched_barrier(0);
      if (lane < 8) {       // publish own 2 rows as 16B MALL stores, no drain
        V16 pv;
        const u64* rq = (const u64*)(rp + xw * 64);
        pv.q[0] = rq[lane * 2]; pv.q[1] = rq[lane * 2 + 1];
        st16_mall(ringp + (size_t)(t + 1) * SLOT + (xw * 2 + (lane >> 2)) * 1024
                  + JB + (lane & 3) * 8, pv.v);
      }
      if (t + 2 < NT) {     // ds_write staged x(t+2) into buf[t&1] (read at t+2)
        short* wb = xbuf + par * 8192 + xw * 2048 + lane * 8;
#pragma unroll
        for (int j = 0; j < 4; ++j)
          *(short8v*)(wb + j * 512) = cvt8(gA[j], gB[j]);
      }
      if (t + 3 < NT) {     // issue gloads x(t+3) (land during next step)
#pragma unroll
        for (int j = 0; j < 4; ++j) {
          const int so = xw * 2048 + j * 512 + lane * 8;
          const float* src = x + ((size_t)(RB + ((so >> 3) & 7)) * NT + (t + 3)) * 1024
                           + (so >> 12) * 512 + ((so >> 6) & 63) * 8;
          gA[j] = *(const float4v*)src; gB[j] = *(const float4v*)(src + 4);
        }
      }
    }
  }

  // ======================= TAIL: out = hT @ Wout^T =========================
  {
    const int ctt = wv & 1, k8 = wv >> 1;   // all 8 waves: (col-tile, K-eighth)
    short8v tw[8], a8t[8];
#pragma unroll
    for (int i = 0; i < 8; ++i) {
      const float* wr = Wout + (size_t)(JB + ctt * 16 + colL) * 1024 + k8 * 256 + i * 32 + kq;
      tw[i] = cvt8(*(const float4v*)wr, *(const float4v*)(wr + 4));
    }
    poll_mall<8>(ringp + (size_t)NT * SLOT + rowA * 1024 + k8 * 256 + kq, a8t);
    f32x4 oc = {0.f,0.f,0.f,0.f};
#pragma unroll
    for (int i = 0; i < 8; ++i)
      oc = __builtin_amdgcn_mfma_f32_16x16x32_bf16(a8t[i], tw[i], oc, 0, 0, 0);
    __syncthreads();          // last epilogue's red reads complete before reuse
    {
      float* rb = red + (wv * 4) * 64 + lane;
#pragma unroll
      for (int reg = 0; reg < 4; ++reg) rb[reg * 64] = oc[reg];
    }
    __syncthreads();
    if (!isH) {
      float o = 0.f;
#pragma unroll
      for (int q2 = 0; q2 < 4; ++q2)
        o += red[((q2 * 2 + ctE) * 4 + rg) * 64 + lsrc];
      out[(size_t)(RB + er) * 1024 + JB + ec] = o;
    }
  }
}

extern "C" void kernel_launch(void* const* d_in, const int* in_sizes, int n_in,
                              void* d_out, int out_size, void* d_ws, size_t ws_size,
                              hipStream_t stream) {
  const float* x    = (const float*)d_in[0];
  const float* h0   = (const float*)d_in[1];
  const float* Wh   = (const float*)d_in[2];
  const float* Wz   = (const float*)d_in[3];
  const float* Uh   = (const float*)d_in[5];
  const float* Uz   = (const float*)d_in[6];
  const float* bz   = (const float*)d_in[8];
  const float* Wout = (const float*)d_in[10];

  // workspace: h-ring only, 8 teams x 513 slots x 16KB = 67.2 MB (proven size)
  short* ring = (short*)d_ws;
  hipMemsetAsync(ring, 0xFF, RING_BYTES, stream);   // sentinel; memset-kernel end
                                                    // release flushes it to MALL
  hipFuncSetAttribute((const void*)gru_kernel,
                      hipFuncAttributeMaxDynamicSharedMemorySize, 90112);
  gru_kernel<<<256, 512, 90112, stream>>>(h0, Wh, Wz, Uh, Uz, bz, Wout, x,
                                          ring, (float*)d_out);
}